// Round 1
// baseline (2608.468 us; speedup 1.0000x reference)
//
#include <hip/hip_runtime.h>
#include <hip/hip_bf16.h>

#define T_SEQ 4096
#define CDIM  768
#define BDIM  8
#define MROWS (BDIM * T_SEQ)   // 32768
#define NKVR  (3 * CDIM)       // 2304

typedef __attribute__((ext_vector_type(8))) short   short8;
typedef __attribute__((ext_vector_type(4))) float   floatx4;
typedef unsigned short ushort_t;

// bf16 <-> f32 helpers on raw ushort storage
__device__ __forceinline__ ushort_t f2b(float f) {
    __hip_bfloat16 h = __float2bfloat16(f);
    return *(ushort_t*)&h;
}
__device__ __forceinline__ float b2f(ushort_t s) {
    __hip_bfloat16 h;
    *(ushort_t*)&h = s;
    return __bfloat162float(h);
}

__device__ __forceinline__ void gload_lds16(const void* g, void* l) {
    __builtin_amdgcn_global_load_lds(
        (const __attribute__((address_space(1))) void*)g,
        (__attribute__((address_space(3))) void*)l, 16, 0, 0);
}

// SHIFTS table: channel group i = c/32 gets shift (dy, dx); out[y][x] = in[y-dy][x-dx]
__constant__ int c_dy[24] = {0,0,1,-1,1,-1,1,-1,0,0,2,-2,2,-2,2,-2,2,1,2,1,-2,-1,-2,-1};
__constant__ int c_dx[24] = {1,-1,0,0,1,-1,-1,1,2,-2,0,0,2,-2,-2,2,1,2,-1,-2,1,2,-1,-2};

// ---------------------------------------------------------------- weights -> bf16
__global__ void cvt_weights(const float* __restrict__ kw, const float* __restrict__ vw,
                            const float* __restrict__ rw, const float* __restrict__ ow,
                            ushort_t* __restrict__ wkvr, ushort_t* __restrict__ wo) {
    int i = blockIdx.x * 256 + threadIdx.x;
    if (i < CDIM * CDIM) {
        wkvr[i]                 = f2b(kw[i]);
        wkvr[i + CDIM * CDIM]   = f2b(vw[i]);
        wkvr[i + 2 * CDIM * CDIM] = f2b(rw[i]);
        wo[i]                   = f2b(ow[i]);
    }
}

// ------------------------------------------------- shift + zigzag reorder + bf16
// xs[b, tz, c] = shifted_x[b, order[tz], c]; order[tz]: r = tz/64, col = pos or 63-pos
__global__ void shift_zigzag(const float* __restrict__ x, ushort_t* __restrict__ xs) {
    size_t i = (size_t)blockIdx.x * 256 + threadIdx.x;
    if (i >= (size_t)MROWS * CDIM) return;
    int c = (int)(i % CDIM);
    size_t bt = i / CDIM;
    int tz = (int)(bt % T_SEQ);
    int b  = (int)(bt / T_SEQ);
    int r = tz >> 6, pos = tz & 63;
    int xcol = (r & 1) ? (63 - pos) : pos;
    int g = c >> 5;
    int ys = r - c_dy[g];
    int xsrc = xcol - c_dx[g];
    float val = 0.0f;
    if ((unsigned)ys < 64u && (unsigned)xsrc < 64u)
        val = x[((size_t)b * T_SEQ + (size_t)(ys * 64 + xsrc)) * CDIM + c];
    xs[i] = f2b(val);
}

// ---------------------------------------------------------------- bf16 MFMA GEMM
// C[m,n] = sum_k A[m,k] * W[n,k]; 128x128 tile, BK=32, 256 threads (4 waves 2x2).
// MODE 0: N=2304, split k/v/sigmoid(r). MODE 1: N=768, fp32 out.
template <int MODE>
__global__ __launch_bounds__(256) void gemm_bt(
    const ushort_t* __restrict__ A, const ushort_t* __restrict__ Bw,
    float* __restrict__ out_k, float* __restrict__ out_v,
    ushort_t* __restrict__ out_sr, float* __restrict__ out_f) {
    __shared__ ushort_t As[128 * 32];
    __shared__ ushort_t Bs[128 * 32];
    const int t    = threadIdx.x;
    const int m0   = blockIdx.x * 128;
    const int n0   = blockIdx.y * 128;
    const int lane = t & 63;
    const int wv   = t >> 6;
    const int wm   = (wv & 1) * 64;
    const int wn   = (wv >> 1) * 64;
    const int row  = t >> 2;        // 0..63
    const int kb   = (t & 3) * 8;   // element offset in K-slice
    const int l15  = lane & 15;
    const int l4   = lane >> 4;

    floatx4 acc[4][4];
#pragma unroll
    for (int i = 0; i < 4; i++)
#pragma unroll
        for (int j = 0; j < 4; j++) acc[i][j] = (floatx4){0.f, 0.f, 0.f, 0.f};

    for (int kk = 0; kk < CDIM; kk += 32) {
        __syncthreads();
        gload_lds16(A  + (size_t)(m0 + row)      * CDIM + kk + kb, (void*)(As + t * 8));
        gload_lds16(A  + (size_t)(m0 + 64 + row) * CDIM + kk + kb, (void*)(As + 2048 + t * 8));
        gload_lds16(Bw + (size_t)(n0 + row)      * CDIM + kk + kb, (void*)(Bs + t * 8));
        gload_lds16(Bw + (size_t)(n0 + 64 + row) * CDIM + kk + kb, (void*)(Bs + 2048 + t * 8));
        __syncthreads();
        short8 af[4], bfv[4];
#pragma unroll
        for (int mi = 0; mi < 4; mi++)
            af[mi] = *(const short8*)(As + (wm + mi * 16 + l15) * 32 + l4 * 8);
#pragma unroll
        for (int ni = 0; ni < 4; ni++)
            bfv[ni] = *(const short8*)(Bs + (wn + ni * 16 + l15) * 32 + l4 * 8);
#pragma unroll
        for (int mi = 0; mi < 4; mi++)
#pragma unroll
            for (int ni = 0; ni < 4; ni++)
                acc[mi][ni] = __builtin_amdgcn_mfma_f32_16x16x32_bf16(
                    af[mi], bfv[ni], acc[mi][ni], 0, 0, 0);
    }

#pragma unroll
    for (int mi = 0; mi < 4; mi++) {
#pragma unroll
        for (int ni = 0; ni < 4; ni++) {
            int ng = n0 + wn + ni * 16 + l15;
#pragma unroll
            for (int r = 0; r < 4; r++) {
                int mg = m0 + wm + mi * 16 + l4 * 4 + r;
                float val = acc[mi][ni][r];
                if (MODE == 0) {
                    if (ng < CDIM)
                        out_k[(size_t)mg * CDIM + ng] = val;
                    else if (ng < 2 * CDIM)
                        out_v[(size_t)mg * CDIM + (ng - CDIM)] = val;
                    else
                        out_sr[(size_t)mg * CDIM + (ng - 2 * CDIM)] =
                            f2b(1.0f / (1.0f + __expf(-val)));
                } else {
                    out_f[(size_t)mg * CDIM + ng] = val;
                }
            }
        }
    }
}

// ---------------------------------------------------------------- WKV pass 1
// sequence order = row order of k/v buffers (zigzag order). In-place on vbuf.
__global__ __launch_bounds__(64) void wkv_pass1(const float* __restrict__ kbuf,
                                                float* __restrict__ vbuf,
                                                const float* __restrict__ sd,
                                                const float* __restrict__ sf) {
    int gid = blockIdx.x * 64 + threadIdx.x;   // 0..6143
    int b = gid / CDIM, c = gid % CDIM;
    const float w = sd[c] * (1.0f / (float)T_SEQ);
    const float u = sf[c] * (1.0f / (float)T_SEQ);
    const float* kp = kbuf + (size_t)b * T_SEQ * CDIM + c;
    float* vp = vbuf + (size_t)b * T_SEQ * CDIM + c;
    float p = 0.f, q = 0.f, o = -1e38f;
    float kt = kp[0], vt = vp[0];
    for (int tt = 0; tt < T_SEQ; tt++) {
        float kn = 0.f, vn = 0.f;
        if (tt + 1 < T_SEQ) {
            kn = kp[(size_t)(tt + 1) * CDIM];
            vn = vp[(size_t)(tt + 1) * CDIM];
        }
        float uk = u + kt;
        float no = fmaxf(o, uk);
        float Ae = __expf(o - no), Be = __expf(uk - no);
        float y = (Ae * p + Be * vt) / (Ae * q + Be);
        float wo_ = w + o;
        float no2 = fmaxf(wo_, kt);
        float A2 = __expf(wo_ - no2), B2 = __expf(kt - no2);
        p = A2 * p + B2 * vt;
        q = A2 * q + B2;
        o = no2;
        vp[(size_t)tt * CDIM] = y;
        kt = kn; vt = vn;
    }
}

// ---------------------------------------------------------------- WKV pass 2
// raster-order scan: step t2 uses zigzag row p(t2)=r*64+col (involution).
// writes a2[p(t2)] = bf16(y * sr[p(t2)])  -> final A for output GEMM, zigzag rows.
__global__ __launch_bounds__(64) void wkv_pass2(const float* __restrict__ kbuf,
                                                const float* __restrict__ vbuf,
                                                const ushort_t* __restrict__ srb,
                                                ushort_t* __restrict__ a2,
                                                const float* __restrict__ sd,
                                                const float* __restrict__ sf) {
    int gid = blockIdx.x * 64 + threadIdx.x;
    int b = gid / CDIM, c = gid % CDIM;
    const float w = sd[CDIM + c] * (1.0f / (float)T_SEQ);
    const float u = sf[CDIM + c] * (1.0f / (float)T_SEQ);
    size_t base = (size_t)b * T_SEQ * CDIM + c;
    float p = 0.f, q = 0.f, o = -1e38f;
    for (int t2 = 0; t2 < T_SEQ; t2++) {
        int r = t2 >> 6, pos = t2 & 63;
        int col = (r & 1) ? (63 - pos) : pos;
        size_t off = base + (size_t)(r * 64 + col) * CDIM;
        float kt = kbuf[off], vt = vbuf[off];
        float uk = u + kt;
        float no = fmaxf(o, uk);
        float Ae = __expf(o - no), Be = __expf(uk - no);
        float y = (Ae * p + Be * vt) / (Ae * q + Be);
        float wo_ = w + o;
        float no2 = fmaxf(wo_, kt);
        float A2 = __expf(wo_ - no2), B2 = __expf(kt - no2);
        p = A2 * p + B2 * vt;
        q = A2 * q + B2;
        o = no2;
        a2[off] = f2b(y * b2f(srb[off]));
    }
}

// ----------------------------------------------------------------------- launch
extern "C" void kernel_launch(void* const* d_in, const int* in_sizes, int n_in,
                              void* d_out, int out_size, void* d_ws, size_t ws_size,
                              hipStream_t stream) {
    (void)in_sizes; (void)n_in; (void)out_size; (void)ws_size;
    const float* x  = (const float*)d_in[0];
    const float* kw = (const float*)d_in[1];
    const float* vw = (const float*)d_in[2];
    const float* rw = (const float*)d_in[3];
    const float* ow = (const float*)d_in[4];
    const float* sd = (const float*)d_in[5];
    const float* sf = (const float*)d_in[6];
    float* out = (float*)d_out;

    char* ws = (char*)d_ws;
    size_t off = 0;
    auto alloc = [&](size_t bytes) -> void* {
        void* p = ws + off;
        off += (bytes + 255) & ~(size_t)255;
        return p;
    };
    ushort_t* xs   = (ushort_t*)alloc((size_t)MROWS * CDIM * 2);  // also reused as a2
    float*    kbuf = (float*)   alloc((size_t)MROWS * CDIM * 4);
    float*    vbuf = (float*)   alloc((size_t)MROWS * CDIM * 4);
    ushort_t* srb  = (ushort_t*)alloc((size_t)MROWS * CDIM * 2);
    ushort_t* wkvr = (ushort_t*)alloc((size_t)NKVR * CDIM * 2);
    ushort_t* wo   = (ushort_t*)alloc((size_t)CDIM * CDIM * 2);

    cvt_weights<<<(CDIM * CDIM + 255) / 256, 256, 0, stream>>>(kw, vw, rw, ow, wkvr, wo);
    shift_zigzag<<<(int)(((size_t)MROWS * CDIM + 255) / 256), 256, 0, stream>>>(x, xs);
    gemm_bt<0><<<dim3(MROWS / 128, NKVR / 128), 256, 0, stream>>>(
        xs, wkvr, kbuf, vbuf, srb, nullptr);
    wkv_pass1<<<MROWS * 0 + (BDIM * CDIM) / 64, 64, 0, stream>>>(kbuf, vbuf, sd, sf);
    // wkv_pass2 writes a2 into the xs buffer (xs dead after gemm1)
    wkv_pass2<<<(BDIM * CDIM) / 64, 64, 0, stream>>>(kbuf, vbuf, srb, xs, sd, sf);
    gemm_bt<1><<<dim3(MROWS / 128, CDIM / 128), 256, 0, stream>>>(
        xs, wo, nullptr, nullptr, nullptr, out);
}

// Round 2
// 714.642 us; speedup vs baseline: 3.6500x; 3.6500x over previous
//
#include <hip/hip_runtime.h>
#include <hip/hip_bf16.h>

#define T_SEQ 4096
#define CDIM  768
#define BDIM  8
#define MROWS (BDIM * T_SEQ)   // 32768
#define NKVR  (3 * CDIM)       // 2304
#define CHL   64               // chunk length (== one raster row)
#define NCH   (T_SEQ / CHL)    // 64 chunks
#define BC    (BDIM * CDIM)    // 6144 independent recurrences

typedef __attribute__((ext_vector_type(8))) short   short8;
typedef __attribute__((ext_vector_type(4))) float   floatx4;
typedef unsigned short ushort_t;

__device__ __forceinline__ ushort_t f2b(float f) {
    __hip_bfloat16 h = __float2bfloat16(f);
    return *(ushort_t*)&h;
}
__device__ __forceinline__ float b2f(ushort_t s) {
    __hip_bfloat16 h;
    *(ushort_t*)&h = s;
    return __bfloat162float(h);
}

__device__ __forceinline__ void gload_lds16(const void* g, void* l) {
    __builtin_amdgcn_global_load_lds(
        (const __attribute__((address_space(1))) void*)g,
        (__attribute__((address_space(3))) void*)l, 16, 0, 0);
}

// SHIFTS table: channel group i = c/32 gets shift (dy, dx); out[y][x] = in[y-dy][x-dx]
__constant__ int c_dy[24] = {0,0,1,-1,1,-1,1,-1,0,0,2,-2,2,-2,2,-2,2,1,2,1,-2,-1,-2,-1};
__constant__ int c_dx[24] = {1,-1,0,0,1,-1,-1,1,2,-2,0,0,2,-2,-2,2,1,2,-1,-2,1,2,-1,-2};

// ---------------------------------------------------------------- weights -> bf16
__global__ void cvt_weights(const float* __restrict__ kw, const float* __restrict__ vw,
                            const float* __restrict__ rw, const float* __restrict__ ow,
                            ushort_t* __restrict__ wkvr, ushort_t* __restrict__ wo) {
    int i = blockIdx.x * 256 + threadIdx.x;
    if (i < CDIM * CDIM) {
        wkvr[i]                   = f2b(kw[i]);
        wkvr[i + CDIM * CDIM]     = f2b(vw[i]);
        wkvr[i + 2 * CDIM * CDIM] = f2b(rw[i]);
        wo[i]                     = f2b(ow[i]);
    }
}

// ------------------------------------------------- shift + zigzag reorder + bf16
__global__ void shift_zigzag(const float* __restrict__ x, ushort_t* __restrict__ xs) {
    size_t i = (size_t)blockIdx.x * 256 + threadIdx.x;
    if (i >= (size_t)MROWS * CDIM) return;
    int c = (int)(i % CDIM);
    size_t bt = i / CDIM;
    int tz = (int)(bt % T_SEQ);
    int b  = (int)(bt / T_SEQ);
    int r = tz >> 6, pos = tz & 63;
    int xcol = (r & 1) ? (63 - pos) : pos;
    int g = c >> 5;
    int ys = r - c_dy[g];
    int xsrc = xcol - c_dx[g];
    float val = 0.0f;
    if ((unsigned)ys < 64u && (unsigned)xsrc < 64u)
        val = x[((size_t)b * T_SEQ + (size_t)(ys * 64 + xsrc)) * CDIM + c];
    xs[i] = f2b(val);
}

// ---------------------------------------------------------------- bf16 MFMA GEMM
// C[m,n] = sum_k A[m,k] * W[n,k]; 128x128 tile, BK=32, 256 threads (4 waves 2x2).
template <int MODE>
__global__ __launch_bounds__(256) void gemm_bt(
    const ushort_t* __restrict__ A, const ushort_t* __restrict__ Bw,
    float* __restrict__ out_k, float* __restrict__ out_v,
    ushort_t* __restrict__ out_sr, float* __restrict__ out_f) {
    __shared__ ushort_t As[128 * 32];
    __shared__ ushort_t Bs[128 * 32];
    const int t    = threadIdx.x;
    const int m0   = blockIdx.x * 128;
    const int n0   = blockIdx.y * 128;
    const int lane = t & 63;
    const int wv   = t >> 6;
    const int wm   = (wv & 1) * 64;
    const int wn   = (wv >> 1) * 64;
    const int row  = t >> 2;
    const int kb   = (t & 3) * 8;
    const int l15  = lane & 15;
    const int l4   = lane >> 4;

    floatx4 acc[4][4];
#pragma unroll
    for (int i = 0; i < 4; i++)
#pragma unroll
        for (int j = 0; j < 4; j++) acc[i][j] = (floatx4){0.f, 0.f, 0.f, 0.f};

    for (int kk = 0; kk < CDIM; kk += 32) {
        __syncthreads();
        gload_lds16(A  + (size_t)(m0 + row)      * CDIM + kk + kb, (void*)(As + t * 8));
        gload_lds16(A  + (size_t)(m0 + 64 + row) * CDIM + kk + kb, (void*)(As + 2048 + t * 8));
        gload_lds16(Bw + (size_t)(n0 + row)      * CDIM + kk + kb, (void*)(Bs + t * 8));
        gload_lds16(Bw + (size_t)(n0 + 64 + row) * CDIM + kk + kb, (void*)(Bs + 2048 + t * 8));
        __syncthreads();
        short8 af[4], bfv[4];
#pragma unroll
        for (int mi = 0; mi < 4; mi++)
            af[mi] = *(const short8*)(As + (wm + mi * 16 + l15) * 32 + l4 * 8);
#pragma unroll
        for (int ni = 0; ni < 4; ni++)
            bfv[ni] = *(const short8*)(Bs + (wn + ni * 16 + l15) * 32 + l4 * 8);
#pragma unroll
        for (int mi = 0; mi < 4; mi++)
#pragma unroll
            for (int ni = 0; ni < 4; ni++)
                acc[mi][ni] = __builtin_amdgcn_mfma_f32_16x16x32_bf16(
                    af[mi], bfv[ni], acc[mi][ni], 0, 0, 0);
    }

#pragma unroll
    for (int mi = 0; mi < 4; mi++) {
#pragma unroll
        for (int ni = 0; ni < 4; ni++) {
            int ng = n0 + wn + ni * 16 + l15;
#pragma unroll
            for (int r = 0; r < 4; r++) {
                int mg = m0 + wm + mi * 16 + l4 * 4 + r;
                float val = acc[mi][ni][r];
                if (MODE == 0) {
                    if (ng < CDIM)
                        out_k[(size_t)mg * CDIM + ng] = val;
                    else if (ng < 2 * CDIM)
                        out_v[(size_t)mg * CDIM + (ng - CDIM)] = val;
                    else
                        out_sr[(size_t)mg * CDIM + (ng - 2 * CDIM)] =
                            f2b(1.0f / (1.0f + __expf(-val)));
                } else {
                    out_f[(size_t)mg * CDIM + ng] = val;
                }
            }
        }
    }
}

// ------------------------------------------------------------- WKV chunked scan
// Recurrence: P' = e^w P + e^{k} v ; state kept max-normalized as (p,q,o).
// PASS 0: sequence = zigzag row order (identity on rows of k/v buffers).
// PASS 1: sequence = raster order; step t2 -> row ch*64 + (ch odd ? 63-i : i).

// Phase A: per-chunk local summary starting from empty state.
template <int PASS>
__global__ __launch_bounds__(256) void wkv_chunk_sum(
    const float* __restrict__ kbuf, const float* __restrict__ vbuf,
    const float* __restrict__ sd,
    float* __restrict__ sumP, float* __restrict__ sumQ, float* __restrict__ sumO) {
    int gid = blockIdx.x * 256 + threadIdx.x;
    int bc = gid % BC;
    int ch = gid / BC;
    int b = bc / CDIM, c = bc % CDIM;
    const float w = sd[PASS * CDIM + c] * (1.0f / (float)T_SEQ);
    size_t base = (size_t)b * T_SEQ * CDIM + c;
    float p = 0.f, q = 0.f, o = -1e38f;
#pragma unroll 4
    for (int i = 0; i < CHL; i++) {
        int row = (PASS == 0) ? (ch * CHL + i)
                              : (ch * CHL + ((ch & 1) ? (CHL - 1 - i) : i));
        size_t off = base + (size_t)row * CDIM;
        float kt = kbuf[off], vt = vbuf[off];
        float wo_ = w + o;
        float no2 = fmaxf(wo_, kt);
        float A2 = __expf(wo_ - no2), B2 = __expf(kt - no2);
        p = A2 * p + B2 * vt;
        q = A2 * q + B2;
        o = no2;
    }
    size_t idx = (size_t)ch * BC + bc;
    sumP[idx] = p; sumQ[idx] = q; sumO[idx] = o;
}

// Phase B: sequential combine of chunk summaries; writes incoming state per chunk.
__global__ __launch_bounds__(256) void wkv_chunk_scan(
    const float* __restrict__ sumP, const float* __restrict__ sumQ,
    const float* __restrict__ sumO,
    float* __restrict__ inP, float* __restrict__ inQ, float* __restrict__ inO,
    const float* __restrict__ sd, int pass) {
    int bc = blockIdx.x * 256 + threadIdx.x;
    if (bc >= BC) return;
    int c = bc % CDIM;
    const float w = sd[pass * CDIM + c] * (1.0f / (float)T_SEQ);
    const float Lw = w * (float)CHL;
    float p = 0.f, q = 0.f, o = -1e38f;
    for (int ch = 0; ch < NCH; ch++) {
        size_t idx = (size_t)ch * BC + bc;
        inP[idx] = p; inQ[idx] = q; inO[idx] = o;
        float Pc = sumP[idx], Qc = sumQ[idx], Oc = sumO[idx];
        float ow_ = o + Lw;
        float no = fmaxf(ow_, Oc);
        float e1 = __expf(ow_ - no), e2 = __expf(Oc - no);
        p = e1 * p + e2 * Pc;
        q = e1 * q + e2 * Qc;
        o = no;
    }
}

// Phase C: replay chunk from incoming state, emit y.
// PASS 0: y -> vbuf in place. PASS 1: a2[off] = bf16(y * sr[off]).
template <int PASS>
__global__ __launch_bounds__(256) void wkv_replay(
    const float* __restrict__ kbuf, float* __restrict__ vbuf,
    const ushort_t* __restrict__ srb, ushort_t* __restrict__ a2,
    const float* __restrict__ sd, const float* __restrict__ sf,
    const float* __restrict__ inP, const float* __restrict__ inQ,
    const float* __restrict__ inO) {
    int gid = blockIdx.x * 256 + threadIdx.x;
    int bc = gid % BC;
    int ch = gid / BC;
    int b = bc / CDIM, c = bc % CDIM;
    const float w = sd[PASS * CDIM + c] * (1.0f / (float)T_SEQ);
    const float u = sf[PASS * CDIM + c] * (1.0f / (float)T_SEQ);
    size_t base = (size_t)b * T_SEQ * CDIM + c;
    size_t idx = (size_t)ch * BC + bc;
    float p = inP[idx], q = inQ[idx], o = inO[idx];
#pragma unroll 4
    for (int i = 0; i < CHL; i++) {
        int row = (PASS == 0) ? (ch * CHL + i)
                              : (ch * CHL + ((ch & 1) ? (CHL - 1 - i) : i));
        size_t off = base + (size_t)row * CDIM;
        float kt = kbuf[off], vt = vbuf[off];
        float uk = u + kt;
        float no = fmaxf(o, uk);
        float Ae = __expf(o - no), Be = __expf(uk - no);
        float y = (Ae * p + Be * vt) / (Ae * q + Be);
        float wo_ = w + o;
        float no2 = fmaxf(wo_, kt);
        float A2 = __expf(wo_ - no2), B2 = __expf(kt - no2);
        p = A2 * p + B2 * vt;
        q = A2 * q + B2;
        o = no2;
        if (PASS == 0)
            vbuf[off] = y;
        else
            a2[off] = f2b(y * b2f(srb[off]));
    }
}

// ----------------------------------------------------------------------- launch
extern "C" void kernel_launch(void* const* d_in, const int* in_sizes, int n_in,
                              void* d_out, int out_size, void* d_ws, size_t ws_size,
                              hipStream_t stream) {
    (void)in_sizes; (void)n_in; (void)out_size; (void)ws_size;
    const float* x  = (const float*)d_in[0];
    const float* kw = (const float*)d_in[1];
    const float* vw = (const float*)d_in[2];
    const float* rw = (const float*)d_in[3];
    const float* ow = (const float*)d_in[4];
    const float* sd = (const float*)d_in[5];
    const float* sf = (const float*)d_in[6];
    float* out = (float*)d_out;

    char* ws = (char*)d_ws;
    size_t off = 0;
    auto alloc = [&](size_t bytes) -> void* {
        void* p = ws + off;
        off += (bytes + 255) & ~(size_t)255;
        return p;
    };
    ushort_t* xs   = (ushort_t*)alloc((size_t)MROWS * CDIM * 2);  // reused as a2
    float*    kbuf = (float*)   alloc((size_t)MROWS * CDIM * 4);
    float*    vbuf = (float*)   alloc((size_t)MROWS * CDIM * 4);
    ushort_t* srb  = (ushort_t*)alloc((size_t)MROWS * CDIM * 2);
    ushort_t* wkvr = (ushort_t*)alloc((size_t)NKVR * CDIM * 2);
    ushort_t* wo   = (ushort_t*)alloc((size_t)CDIM * CDIM * 2);
    float*    sumP = (float*)   alloc((size_t)NCH * BC * 4);
    float*    sumQ = (float*)   alloc((size_t)NCH * BC * 4);
    float*    sumO = (float*)   alloc((size_t)NCH * BC * 4);
    float*    inP  = (float*)   alloc((size_t)NCH * BC * 4);
    float*    inQ  = (float*)   alloc((size_t)NCH * BC * 4);
    float*    inO  = (float*)   alloc((size_t)NCH * BC * 4);

    cvt_weights<<<(CDIM * CDIM + 255) / 256, 256, 0, stream>>>(kw, vw, rw, ow, wkvr, wo);
    shift_zigzag<<<(int)(((size_t)MROWS * CDIM + 255) / 256), 256, 0, stream>>>(x, xs);
    gemm_bt<0><<<dim3(MROWS / 128, NKVR / 128), 256, 0, stream>>>(
        xs, wkvr, kbuf, vbuf, srb, nullptr);

    const int nwkv = NCH * BC;  // 393216 threads
    // ---- pass 1 (zigzag order), in-place on vbuf
    wkv_chunk_sum<0><<<nwkv / 256, 256, 0, stream>>>(kbuf, vbuf, sd, sumP, sumQ, sumO);
    wkv_chunk_scan<<<(BC + 255) / 256, 256, 0, stream>>>(sumP, sumQ, sumO,
                                                         inP, inQ, inO, sd, 0);
    wkv_replay<0><<<nwkv / 256, 256, 0, stream>>>(kbuf, vbuf, nullptr, nullptr,
                                                  sd, sf, inP, inQ, inO);
    // ---- pass 2 (raster order), emits a2 = bf16(y * sr) into xs buffer
    wkv_chunk_sum<1><<<nwkv / 256, 256, 0, stream>>>(kbuf, vbuf, sd, sumP, sumQ, sumO);
    wkv_chunk_scan<<<(BC + 255) / 256, 256, 0, stream>>>(sumP, sumQ, sumO,
                                                         inP, inQ, inO, sd, 1);
    wkv_replay<1><<<nwkv / 256, 256, 0, stream>>>(kbuf, vbuf, srb, xs,
                                                  sd, sf, inP, inQ, inO);

    gemm_bt<1><<<dim3(MROWS / 128, CDIM / 128), 256, 0, stream>>>(
        xs, wo, nullptr, nullptr, nullptr, out);
}